// Round 17
// baseline (578.310 us; speedup 1.0000x reference)
//
#include <hip/hip_runtime.h>
#include <hip/hip_bf16.h>

#define BS 32
#define QL 16
#define KV 2048
#define NH 16
#define DK 128
#define DM 2048
#define MROWS (BS*QL)   // 512
#define KCA 2           // fused-kernel k-chunks (1024 rows each) -> 1024 blocks, 1 pass
#define AROWS (KV/KCA)
#define SPLICE (KV-QL)  // 2032

#define SCALE 0.08838834764831845f  // 1/sqrt(128)
#define LOG2E 1.4426950408889634f

typedef __bf16 bf16x8 __attribute__((ext_vector_type(8)));
typedef float f32x4 __attribute__((ext_vector_type(4)));
typedef unsigned short us8 __attribute__((ext_vector_type(8)));
typedef unsigned short us4 __attribute__((ext_vector_type(4)));

__device__ inline unsigned short f2bf(float f){
    unsigned u = __builtin_bit_cast(unsigned, f);
    u += 0x7fffu + ((u >> 16) & 1u);
    return (unsigned short)(u >> 16);
}
__device__ inline float bf2f(unsigned short u){
    unsigned x = ((unsigned)u) << 16;
    return __builtin_bit_cast(float, x);
}

// Convert f32 tensors to bf16 (x + 4 weight matrices). grid (1024, 5).
__global__ __launch_bounds__(256) void prep_bf16(
    const float* __restrict__ s0, const float* __restrict__ s1,
    const float* __restrict__ s2, const float* __restrict__ s3,
    const float* __restrict__ s4,
    __hip_bfloat16* __restrict__ d0, __hip_bfloat16* __restrict__ d1,
    __hip_bfloat16* __restrict__ d2, __hip_bfloat16* __restrict__ d3,
    __hip_bfloat16* __restrict__ d4)
{
    int z = blockIdx.y;
    const float* s = (z==0)?s0:(z==1)?s1:(z==2)?s2:(z==3)?s3:s4;
    unsigned short* d = (unsigned short*)((z==0)?d0:(z==1)?d1:(z==2)?d2:(z==3)?d3:d4);
    int n8 = (z==0) ? (MROWS*DM/8) : (DM*DM/8);

    int stride = gridDim.x * 256;
    for (int i = blockIdx.x*256 + threadIdx.x; i < n8; i += stride) {
        const float* p = s + (size_t)i*8;
        float4 a0 = *(const float4*)p;
        float4 a1 = *(const float4*)(p + 4);
        us8 v = { f2bf(a0.x), f2bf(a0.y), f2bf(a0.z), f2bf(a0.w),
                  f2bf(a1.x), f2bf(a1.y), f2bf(a1.z), f2bf(a1.w) };
        *(us8*)&d[(size_t)i*8] = v;
    }
}

// C[m][n] = sum_k A[m][k] * W[n][k] + bias[n]; A and W are bf16, 64x64 tiles.
// bfScaleMask bit z: write (acc+bias)*SCALE as bf16 to Cbf instead of f32 to C.
__global__ __launch_bounds__(256) void gemm_bt(
    const __hip_bfloat16* __restrict__ A0p,
    const __hip_bfloat16* __restrict__ W0, const __hip_bfloat16* __restrict__ W1,
    const __hip_bfloat16* __restrict__ W2,
    const float* __restrict__ b0, const float* __restrict__ b1, const float* __restrict__ b2,
    float* __restrict__ C0, float* __restrict__ C1, float* __restrict__ C2,
    __hip_bfloat16* __restrict__ Cbf,
    int spliceMask, int bfScaleMask)
{
    int z = blockIdx.z;
    const unsigned short* W = (const unsigned short*)((z==0)?W0:(z==1)?W1:W2);
    const unsigned short* A = (const unsigned short*)A0p;
    const float* bias = (z==0)?b0:(z==1)?b1:b2;
    float*       C    = (z==0)?C0:(z==1)?C1:C2;
    int spl = (spliceMask >> z) & 1;
    int bfo = (bfScaleMask >> z) & 1;

    const int K = DM, N = DM;
    int mBase = blockIdx.x * 64, nBase = blockIdx.y * 64;

    __shared__ __align__(16) unsigned short As[64*40];
    __shared__ __align__(16) unsigned short Bs[64*40];

    int t = threadIdx.x;
    int wv = t >> 6, lane = t & 63;
    int row = t >> 2, seg = (t & 3) * 8;
    int g = lane >> 4, c = lane & 15;

    f32x4 acc[4] = {{0,0,0,0},{0,0,0,0},{0,0,0,0},{0,0,0,0}};

    for (int k0 = 0; k0 < K; k0 += 32) {
        __syncthreads();
        *(us8*)&As[row*40 + seg] = *(const us8*)&A[(size_t)(mBase + row)*K + k0 + seg];
        *(us8*)&Bs[row*40 + seg] = *(const us8*)&W[(size_t)(nBase + row)*K + k0 + seg];
        __syncthreads();

        bf16x8 af = __builtin_bit_cast(bf16x8, *(us8*)&As[(wv*16 + c)*40 + g*8]);
        #pragma unroll
        for (int j = 0; j < 4; j++) {
            bf16x8 bf = __builtin_bit_cast(bf16x8, *(us8*)&Bs[(j*16 + c)*40 + g*8]);
            acc[j] = __builtin_amdgcn_mfma_f32_16x16x32_bf16(af, bf, acc[j], 0, 0, 0);
        }
    }

    #pragma unroll
    for (int j = 0; j < 4; j++) {
        int n = nBase + j*16 + c;
        float bb = bias[n];
        #pragma unroll
        for (int r = 0; r < 4; r++) {
            int m = mBase + wv*16 + g*4 + r;
            if (bfo) {
                ((unsigned short*)Cbf)[(size_t)m * N + n] = f2bf((acc[j][r] + bb) * SCALE);
            } else {
                size_t rowoff = spl ? ((size_t)(m >> 4) * KV + SPLICE + (m & 15)) * (size_t)N
                                    : (size_t)m * (size_t)N;
                C[rowoff + n] = acc[j][r] + bb;
            }
        }
    }
}

// Fused K-copy + QK^T + V-copy + PV (max-free softmax). R15 body, KCA=2.
__global__ __launch_bounds__(256) void fused_kv_attn(
    const __hip_bfloat16* __restrict__ qb, const float* __restrict__ kcache,
    const float* __restrict__ vcache, const int* __restrict__ mask,
    float* __restrict__ kout, float* __restrict__ vout,
    __hip_bfloat16* __restrict__ Obuf, float* __restrict__ Lbuf)
{
    int h = blockIdx.x, b = blockIdx.y, kc = blockIdx.z;
    int t = threadIdx.x, wv = t >> 6, lane = t & 63;
    int g = lane >> 4, c = lane & 15;
    size_t bKV = (size_t)b * KV;
    size_t bh  = (size_t)b * NH + h;
    unsigned short* Ob = (unsigned short*)Obuf;

    __shared__ __align__(16) unsigned char smem[4*16*132*4];
    unsigned short* Vl = (unsigned short*)smem;
    float* redf = (float*)smem;
    __shared__ float smL[4][16];

    // Q fragments (pre-scaled bf16): 4 direct us8 loads
    bf16x8 af[4];
    {
        const unsigned short* qp = (const unsigned short*)qb
                                 + (size_t)(b*QL + c) * DM + h*DK + g*8;
        #pragma unroll
        for (int ks = 0; ks < 4; ks++)
            af[ks] = __builtin_bit_cast(bf16x8, *(const us8*)(qp + ks*32));
    }

    f32x4 Oacc[8];
    #pragma unroll
    for (int nt = 0; nt < 8; nt++) Oacc[nt] = (f32x4){0,0,0,0};
    float lacc = 0.f;

    unsigned short* Vw = Vl + wv*2304;

    for (int i = 0; i < AROWS/64; i++) {
        int n0 = kc*AROWS + (i*4 + wv)*16;
        bool spl = (n0 >= SPLICE);

        int krow = n0 + c;
        const float* ksrc = (spl ? kout : kcache) + (bKV + krow)*DM + h*DK + g*8;
        float4 kvv[8];
        #pragma unroll
        for (int ks = 0; ks < 4; ks++) {
            kvv[2*ks]   = *(const float4*)(ksrc + ks*32);
            kvv[2*ks+1] = *(const float4*)(ksrc + ks*32 + 4);
        }

        #pragma unroll
        for (int f = 0; f < 8; f++) {
            int k  = (f & 1)*8 + (lane >> 3);
            int d0 = ((lane & 7)*4) + (f >> 1)*32;
            size_t off = (bKV + n0 + k)*DM + h*DK + d0;
            float4 v = *(const float4*)((spl ? vout : vcache) + off);
            if (!spl) *(float4*)(vout + off) = v;
            int e = (d0 >> 4)*288 + (k >> 2)*72 + (k & 3)*16 + (d0 & 15);
            us4 bv4 = { f2bf(v.x), f2bf(v.y), f2bf(v.z), f2bf(v.w) };
            *(us4*)&Vw[e] = bv4;
        }

        if (!spl) {
            float* kdst = kout + (bKV + krow)*DM + h*DK + g*8;
            #pragma unroll
            for (int ks = 0; ks < 4; ks++) {
                *(float4*)(kdst + ks*32)     = kvv[2*ks];
                *(float4*)(kdst + ks*32 + 4) = kvv[2*ks+1];
            }
        }

        f32x4 sc = {0,0,0,0};
        #pragma unroll
        for (int ks = 0; ks < 4; ks++) {
            float4 k0 = kvv[2*ks], k1 = kvv[2*ks+1];
            us8 kb = { f2bf(k0.x), f2bf(k0.y), f2bf(k0.z), f2bf(k0.w),
                       f2bf(k1.x), f2bf(k1.y), f2bf(k1.z), f2bf(k1.w) };
            sc = __builtin_amdgcn_mfma_f32_16x16x32_bf16(
                    __builtin_bit_cast(bf16x8, kb), af[ks], sc, 0, 0, 0);
        }

        const int4 mv = *(const int4*)(mask + ((size_t)b*QL + c)*KV + n0 + g*4);
        int mi[4] = {mv.x, mv.y, mv.z, mv.w};
        float p[4];
        #pragma unroll
        for (int r = 0; r < 4; r++) {
            p[r] = mi[r] ? exp2f(sc[r]*LOG2E) : 0.f;
            lacc += p[r];
        }
        us8 pa = { f2bf(p[0]), f2bf(p[1]), f2bf(p[2]), f2bf(p[3]), 0, 0, 0, 0 };
        bf16x8 paf = __builtin_bit_cast(bf16x8, pa);

        #pragma unroll
        for (int nt = 0; nt < 8; nt++) {
            const unsigned short* vb = Vw + nt*288 + g*72 + c;
            us8 b8 = { vb[0], vb[16], vb[32], vb[48], 0, 0, 0, 0 };
            Oacc[nt] = __builtin_amdgcn_mfma_f32_16x16x32_bf16(
                          paf, __builtin_bit_cast(bf16x8, b8), Oacc[nt], 0, 0, 0);
        }
    }

    lacc += __shfl_xor(lacc, 16);
    lacc += __shfl_xor(lacc, 32);
    if (lane < 16) smL[wv][lane] = lacc;

    __syncthreads();

    #pragma unroll
    for (int nt = 0; nt < 8; nt++)
        #pragma unroll
        for (int r = 0; r < 4; r++)
            redf[wv*2112 + (g*4 + r)*132 + c + nt*16] = Oacc[nt][r];
    __syncthreads();

    {
        int q = t >> 4, d0 = (t & 15)*8;
        float s[8] = {0,0,0,0,0,0,0,0};
        #pragma unroll
        for (int w = 0; w < 4; w++) {
            float4 x0 = *(const float4*)&redf[w*2112 + q*132 + d0];
            float4 x1 = *(const float4*)&redf[w*2112 + q*132 + d0 + 4];
            s[0]+=x0.x; s[1]+=x0.y; s[2]+=x0.z; s[3]+=x0.w;
            s[4]+=x1.x; s[5]+=x1.y; s[6]+=x1.z; s[7]+=x1.w;
        }
        us8 o = { f2bf(s[0]), f2bf(s[1]), f2bf(s[2]), f2bf(s[3]),
                  f2bf(s[4]), f2bf(s[5]), f2bf(s[6]), f2bf(s[7]) };
        *(us8*)(void*)&Ob[(((size_t)kc*(BS*NH) + bh)*QL + q)*DK + d0] = o;
        if (t < 16)
            Lbuf[(bh*KCA + kc)*QL + t] = smL[0][t] + smL[1][t] + smL[2][t] + smL[3][t];
    }
}

// Normalize + sum the KCA chunk partials into awsb (bf16). 512 blocks x 256 thr.
__global__ __launch_bounds__(256) void attn_combine(
    const __hip_bfloat16* __restrict__ Obuf, const float* __restrict__ Lbuf,
    __hip_bfloat16* __restrict__ awsb)
{
    int idx8 = blockIdx.x * 256 + threadIdx.x;   // unit = 8 values
    int m = idx8 >> 8;                            // output row (0..511)
    int col = (idx8 & 255) * 8;                   // column (0..2040)
    int b = m >> 4, q = m & 15;
    int h = col >> 7, d0 = col & 127;
    size_t bh = (size_t)b * NH + h;
    const unsigned short* Ob = (const unsigned short*)Obuf;

    float L = 0.f;
    #pragma unroll
    for (int kc = 0; kc < KCA; kc++) L += Lbuf[(bh*KCA + kc)*QL + q];
    float inv = 1.0f / L;

    float s[8] = {0,0,0,0,0,0,0,0};
    #pragma unroll
    for (int kc = 0; kc < KCA; kc++) {
        us8 o = *(const us8*)(const void*)&Ob[(((size_t)kc*(BS*NH) + bh)*QL + q)*DK + d0];
        #pragma unroll
        for (int j = 0; j < 8; j++) s[j] += bf2f(o[j]);
    }
    us8 ov = { f2bf(s[0]*inv), f2bf(s[1]*inv), f2bf(s[2]*inv), f2bf(s[3]*inv),
               f2bf(s[4]*inv), f2bf(s[5]*inv), f2bf(s[6]*inv), f2bf(s[7]*inv) };
    *(us8*)(void*)&((unsigned short*)awsb)[(size_t)m * DM + col] = ov;
}

extern "C" void kernel_launch(void* const* d_in, const int* in_sizes, int n_in,
                              void* d_out, int out_size, void* d_ws, size_t ws_size,
                              hipStream_t stream)
{
    (void)in_sizes; (void)n_in; (void)out_size; (void)ws_size;

    const float* x      = (const float*)d_in[0];
    const float* kcache = (const float*)d_in[1];
    const float* vcache = (const float*)d_in[2];
    const int*   mask   = (const int*)  d_in[3];
    const float* Wq     = (const float*)d_in[4];
    const float* bq     = (const float*)d_in[5];
    const float* Wk     = (const float*)d_in[6];
    const float* bk     = (const float*)d_in[7];
    const float* Wv     = (const float*)d_in[8];
    const float* bv     = (const float*)d_in[9];
    const float* Wo     = (const float*)d_in[10];
    const float* bo     = (const float*)d_in[11];

    float* out  = (float*)d_out;
    float* kout = out  + (size_t)MROWS * DM;
    float* vout = kout + (size_t)BS * KV * DM;

    // Compact ws layout with lifetime aliasing (total 44.1 MB):
    //   [0, 8MB)      Obuf (bf16, kernels 2-3, 4MB used); xb aliases head (kernels 0-1)
    //   [8, 40MB)     Wqb, Wkb, Wvb, Wob (bf16, kernels 0-4)
    //   [40, 42MB)    qb (bf16, kernels 1-2); awsb aliases it (kernels 3-4)
    //   [44, 44.13MB) Lbuf (f32, kernels 2-3)
    char* wsb = (char*)d_ws;
    __hip_bfloat16* Obuf = (__hip_bfloat16*)wsb;                      // 4 MB used
    __hip_bfloat16* xb   = (__hip_bfloat16*)wsb;                      // aliases Obuf head
    __hip_bfloat16* Wqb  = (__hip_bfloat16*)(wsb + (8u<<20));
    __hip_bfloat16* Wkb  = Wqb + (size_t)DM * DM;
    __hip_bfloat16* Wvb  = Wkb + (size_t)DM * DM;
    __hip_bfloat16* Wob  = Wvb + (size_t)DM * DM;
    __hip_bfloat16* qb   = (__hip_bfloat16*)(wsb + (40u<<20));        // 2 MB
    __hip_bfloat16* awsb = qb;                                        // aliases qb
    float* Lbuf          = (float*)(wsb + (44u<<20));                 // 64 KB

    // 0) convert x + weights to bf16
    dim3 gp(1024, 5, 1);
    prep_bf16<<<gp, 256, 0, stream>>>(x, Wq, Wk, Wv, Wo, xb, Wqb, Wkb, Wvb, Wob);

    // 1) QKV projections; q written pre-scaled bf16; K/V spliced into caches
    dim3 gq(MROWS/64, DM/64, 3);
    gemm_bt<<<gq, 256, 0, stream>>>(xb, Wqb, Wkb, Wvb, bq, bk, bv,
                                    nullptr, kout, vout, qb, 0b110, 0b001);

    // 2) fused K/V copy + attention partials (1024 blocks = 4/CU, single pass)
    dim3 gf(NH, BS, KCA);
    fused_kv_attn<<<gf, 256, 0, stream>>>(qb, kcache, vcache, mask,
                                          kout, vout, Obuf, Lbuf);

    // 3) normalize + sum chunk partials -> bf16 (overwrites qb)
    attn_combine<<<512, 256, 0, stream>>>(Obuf, Lbuf, awsb);

    // 4) output projection (bf16 operands)
    dim3 go(MROWS/64, DM/64, 1);
    gemm_bt<<<go, 256, 0, stream>>>(awsb, Wob, Wob, Wob, bo, bo, bo,
                                    out, out, out, nullptr, 0, 0);
}

// Round 18
// 553.885 us; speedup vs baseline: 1.0441x; 1.0441x over previous
//
#include <hip/hip_runtime.h>
#include <hip/hip_bf16.h>

#define BS 32
#define QL 16
#define KV 2048
#define NH 16
#define DK 128
#define DM 2048
#define MROWS (BS*QL)   // 512
#define KCA 4           // fused-kernel k-chunks (512 rows each)
#define AROWS (KV/KCA)
#define SPLICE (KV-QL)  // 2032

#define SCALE 0.08838834764831845f  // 1/sqrt(128)
#define LOG2E 1.4426950408889634f

typedef __bf16 bf16x8 __attribute__((ext_vector_type(8)));
typedef float f32x4 __attribute__((ext_vector_type(4)));
typedef unsigned short us8 __attribute__((ext_vector_type(8)));
typedef unsigned short us4 __attribute__((ext_vector_type(4)));

__device__ inline unsigned short f2bf(float f){
    unsigned u = __builtin_bit_cast(unsigned, f);
    u += 0x7fffu + ((u >> 16) & 1u);
    return (unsigned short)(u >> 16);
}
__device__ inline float bf2f(unsigned short u){
    unsigned x = ((unsigned)u) << 16;
    return __builtin_bit_cast(float, x);
}

// Convert f32 tensors to bf16 (x + 4 weight matrices). grid (1024, 5).
__global__ __launch_bounds__(256) void prep_bf16(
    const float* __restrict__ s0, const float* __restrict__ s1,
    const float* __restrict__ s2, const float* __restrict__ s3,
    const float* __restrict__ s4,
    __hip_bfloat16* __restrict__ d0, __hip_bfloat16* __restrict__ d1,
    __hip_bfloat16* __restrict__ d2, __hip_bfloat16* __restrict__ d3,
    __hip_bfloat16* __restrict__ d4)
{
    int z = blockIdx.y;
    const float* s = (z==0)?s0:(z==1)?s1:(z==2)?s2:(z==3)?s3:s4;
    unsigned short* d = (unsigned short*)((z==0)?d0:(z==1)?d1:(z==2)?d2:(z==3)?d3:d4);
    int n8 = (z==0) ? (MROWS*DM/8) : (DM*DM/8);

    int stride = gridDim.x * 256;
    for (int i = blockIdx.x*256 + threadIdx.x; i < n8; i += stride) {
        const float* p = s + (size_t)i*8;
        float4 a0 = *(const float4*)p;
        float4 a1 = *(const float4*)(p + 4);
        us8 v = { f2bf(a0.x), f2bf(a0.y), f2bf(a0.z), f2bf(a0.w),
                  f2bf(a1.x), f2bf(a1.y), f2bf(a1.z), f2bf(a1.w) };
        *(us8*)&d[(size_t)i*8] = v;
    }
}

// C[m][n] = sum_k A[m][k] * W[n][k] + bias[n]; A and W are bf16, 64x64 tiles.
// bfScaleMask bit z: write (acc+bias)*SCALE as bf16 to Cbf instead of f32 to C.
__global__ __launch_bounds__(256) void gemm_bt(
    const __hip_bfloat16* __restrict__ A0p,
    const __hip_bfloat16* __restrict__ W0, const __hip_bfloat16* __restrict__ W1,
    const __hip_bfloat16* __restrict__ W2,
    const float* __restrict__ b0, const float* __restrict__ b1, const float* __restrict__ b2,
    float* __restrict__ C0, float* __restrict__ C1, float* __restrict__ C2,
    __hip_bfloat16* __restrict__ Cbf,
    int spliceMask, int bfScaleMask)
{
    int z = blockIdx.z;
    const unsigned short* W = (const unsigned short*)((z==0)?W0:(z==1)?W1:W2);
    const unsigned short* A = (const unsigned short*)A0p;
    const float* bias = (z==0)?b0:(z==1)?b1:b2;
    float*       C    = (z==0)?C0:(z==1)?C1:C2;
    int spl = (spliceMask >> z) & 1;
    int bfo = (bfScaleMask >> z) & 1;

    const int K = DM, N = DM;
    int mBase = blockIdx.x * 64, nBase = blockIdx.y * 64;

    __shared__ __align__(16) unsigned short As[64*40];
    __shared__ __align__(16) unsigned short Bs[64*40];

    int t = threadIdx.x;
    int wv = t >> 6, lane = t & 63;
    int row = t >> 2, seg = (t & 3) * 8;
    int g = lane >> 4, c = lane & 15;

    f32x4 acc[4] = {{0,0,0,0},{0,0,0,0},{0,0,0,0},{0,0,0,0}};

    for (int k0 = 0; k0 < K; k0 += 32) {
        __syncthreads();
        *(us8*)&As[row*40 + seg] = *(const us8*)&A[(size_t)(mBase + row)*K + k0 + seg];
        *(us8*)&Bs[row*40 + seg] = *(const us8*)&W[(size_t)(nBase + row)*K + k0 + seg];
        __syncthreads();

        bf16x8 af = __builtin_bit_cast(bf16x8, *(us8*)&As[(wv*16 + c)*40 + g*8]);
        #pragma unroll
        for (int j = 0; j < 4; j++) {
            bf16x8 bf = __builtin_bit_cast(bf16x8, *(us8*)&Bs[(j*16 + c)*40 + g*8]);
            acc[j] = __builtin_amdgcn_mfma_f32_16x16x32_bf16(af, bf, acc[j], 0, 0, 0);
        }
    }

    #pragma unroll
    for (int j = 0; j < 4; j++) {
        int n = nBase + j*16 + c;
        float bb = bias[n];
        #pragma unroll
        for (int r = 0; r < 4; r++) {
            int m = mBase + wv*16 + g*4 + r;
            if (bfo) {
                ((unsigned short*)Cbf)[(size_t)m * N + n] = f2bf((acc[j][r] + bb) * SCALE);
            } else {
                size_t rowoff = spl ? ((size_t)(m >> 4) * KV + SPLICE + (m & 15)) * (size_t)N
                                    : (size_t)m * (size_t)N;
                C[rowoff + n] = acc[j][r] + bb;
            }
        }
    }
}

// Fused K-copy + QK^T + V-copy + PV (max-free softmax). R13 body; Q read
// as pre-scaled bf16 fragments.
__global__ __launch_bounds__(256) void fused_kv_attn(
    const __hip_bfloat16* __restrict__ qb, const float* __restrict__ kcache,
    const float* __restrict__ vcache, const int* __restrict__ mask,
    float* __restrict__ kout, float* __restrict__ vout,
    __hip_bfloat16* __restrict__ Obuf, float* __restrict__ Lbuf)
{
    int h = blockIdx.x, b = blockIdx.y, kc = blockIdx.z;
    int t = threadIdx.x, wv = t >> 6, lane = t & 63;
    int g = lane >> 4, c = lane & 15;
    size_t bKV = (size_t)b * KV;
    size_t bh  = (size_t)b * NH + h;
    unsigned short* Ob = (unsigned short*)Obuf;

    __shared__ __align__(16) unsigned char smem[4*16*132*4];
    unsigned short* Vl = (unsigned short*)smem;
    float* redf = (float*)smem;
    __shared__ float smL[4][16];

    // Q fragments (pre-scaled bf16): 4 direct us8 loads
    bf16x8 af[4];
    {
        const unsigned short* qp = (const unsigned short*)qb
                                 + (size_t)(b*QL + c) * DM + h*DK + g*8;
        #pragma unroll
        for (int ks = 0; ks < 4; ks++)
            af[ks] = __builtin_bit_cast(bf16x8, *(const us8*)(qp + ks*32));
    }

    f32x4 Oacc[8];
    #pragma unroll
    for (int nt = 0; nt < 8; nt++) Oacc[nt] = (f32x4){0,0,0,0};
    float lacc = 0.f;

    unsigned short* Vw = Vl + wv*2304;

    for (int i = 0; i < AROWS/64; i++) {
        int n0 = kc*AROWS + (i*4 + wv)*16;
        bool spl = (n0 >= SPLICE);

        int krow = n0 + c;
        const float* ksrc = (spl ? kout : kcache) + (bKV + krow)*DM + h*DK + g*8;
        float4 kvv[8];
        #pragma unroll
        for (int ks = 0; ks < 4; ks++) {
            kvv[2*ks]   = *(const float4*)(ksrc + ks*32);
            kvv[2*ks+1] = *(const float4*)(ksrc + ks*32 + 4);
        }

        #pragma unroll
        for (int f = 0; f < 8; f++) {
            int k  = (f & 1)*8 + (lane >> 3);
            int d0 = ((lane & 7)*4) + (f >> 1)*32;
            size_t off = (bKV + n0 + k)*DM + h*DK + d0;
            float4 v = *(const float4*)((spl ? vout : vcache) + off);
            if (!spl) *(float4*)(vout + off) = v;
            int e = (d0 >> 4)*288 + (k >> 2)*72 + (k & 3)*16 + (d0 & 15);
            us4 bv4 = { f2bf(v.x), f2bf(v.y), f2bf(v.z), f2bf(v.w) };
            *(us4*)&Vw[e] = bv4;
        }

        if (!spl) {
            float* kdst = kout + (bKV + krow)*DM + h*DK + g*8;
            #pragma unroll
            for (int ks = 0; ks < 4; ks++) {
                *(float4*)(kdst + ks*32)     = kvv[2*ks];
                *(float4*)(kdst + ks*32 + 4) = kvv[2*ks+1];
            }
        }

        f32x4 sc = {0,0,0,0};
        #pragma unroll
        for (int ks = 0; ks < 4; ks++) {
            float4 k0 = kvv[2*ks], k1 = kvv[2*ks+1];
            us8 kb = { f2bf(k0.x), f2bf(k0.y), f2bf(k0.z), f2bf(k0.w),
                       f2bf(k1.x), f2bf(k1.y), f2bf(k1.z), f2bf(k1.w) };
            sc = __builtin_amdgcn_mfma_f32_16x16x32_bf16(
                    __builtin_bit_cast(bf16x8, kb), af[ks], sc, 0, 0, 0);
        }

        const int4 mv = *(const int4*)(mask + ((size_t)b*QL + c)*KV + n0 + g*4);
        int mi[4] = {mv.x, mv.y, mv.z, mv.w};
        float p[4];
        #pragma unroll
        for (int r = 0; r < 4; r++) {
            p[r] = mi[r] ? exp2f(sc[r]*LOG2E) : 0.f;
            lacc += p[r];
        }
        us8 pa = { f2bf(p[0]), f2bf(p[1]), f2bf(p[2]), f2bf(p[3]), 0, 0, 0, 0 };
        bf16x8 paf = __builtin_bit_cast(bf16x8, pa);

        #pragma unroll
        for (int nt = 0; nt < 8; nt++) {
            const unsigned short* vb = Vw + nt*288 + g*72 + c;
            us8 b8 = { vb[0], vb[16], vb[32], vb[48], 0, 0, 0, 0 };
            Oacc[nt] = __builtin_amdgcn_mfma_f32_16x16x32_bf16(
                          paf, __builtin_bit_cast(bf16x8, b8), Oacc[nt], 0, 0, 0);
        }
    }

    lacc += __shfl_xor(lacc, 16);
    lacc += __shfl_xor(lacc, 32);
    if (lane < 16) smL[wv][lane] = lacc;

    __syncthreads();

    #pragma unroll
    for (int nt = 0; nt < 8; nt++)
        #pragma unroll
        for (int r = 0; r < 4; r++)
            redf[wv*2112 + (g*4 + r)*132 + c + nt*16] = Oacc[nt][r];
    __syncthreads();

    {
        int q = t >> 4, d0 = (t & 15)*8;
        float s[8] = {0,0,0,0,0,0,0,0};
        #pragma unroll
        for (int w = 0; w < 4; w++) {
            float4 x0 = *(const float4*)&redf[w*2112 + q*132 + d0];
            float4 x1 = *(const float4*)&redf[w*2112 + q*132 + d0 + 4];
            s[0]+=x0.x; s[1]+=x0.y; s[2]+=x0.z; s[3]+=x0.w;
            s[4]+=x1.x; s[5]+=x1.y; s[6]+=x1.z; s[7]+=x1.w;
        }
        us8 o = { f2bf(s[0]), f2bf(s[1]), f2bf(s[2]), f2bf(s[3]),
                  f2bf(s[4]), f2bf(s[5]), f2bf(s[6]), f2bf(s[7]) };
        *(us8*)(void*)&Ob[(((size_t)kc*(BS*NH) + bh)*QL + q)*DK + d0] = o;
        if (t < 16)
            Lbuf[(bh*KCA + kc)*QL + t] = smL[0][t] + smL[1][t] + smL[2][t] + smL[3][t];
    }
}

// Normalize + sum the KCA chunk partials into awsb (bf16). 512 blocks x 256 thr.
__global__ __launch_bounds__(256) void attn_combine(
    const __hip_bfloat16* __restrict__ Obuf, const float* __restrict__ Lbuf,
    __hip_bfloat16* __restrict__ awsb)
{
    int idx8 = blockIdx.x * 256 + threadIdx.x;   // unit = 8 values
    int m = idx8 >> 8;                            // output row (0..511)
    int col = (idx8 & 255) * 8;                   // column (0..2040)
    int b = m >> 4, q = m & 15;
    int h = col >> 7, d0 = col & 127;
    size_t bh = (size_t)b * NH + h;
    const unsigned short* Ob = (const unsigned short*)Obuf;

    float L = 0.f;
    #pragma unroll
    for (int kc = 0; kc < KCA; kc++) L += Lbuf[(bh*KCA + kc)*QL + q];
    float inv = 1.0f / L;

    float s[8] = {0,0,0,0,0,0,0,0};
    #pragma unroll
    for (int kc = 0; kc < KCA; kc++) {
        us8 o = *(const us8*)(const void*)&Ob[(((size_t)kc*(BS*NH) + bh)*QL + q)*DK + d0];
        #pragma unroll
        for (int j = 0; j < 8; j++) s[j] += bf2f(o[j]);
    }
    us8 ov = { f2bf(s[0]*inv), f2bf(s[1]*inv), f2bf(s[2]*inv), f2bf(s[3]*inv),
               f2bf(s[4]*inv), f2bf(s[5]*inv), f2bf(s[6]*inv), f2bf(s[7]*inv) };
    *(us8*)(void*)&((unsigned short*)awsb)[(size_t)m * DM + col] = ov;
}

extern "C" void kernel_launch(void* const* d_in, const int* in_sizes, int n_in,
                              void* d_out, int out_size, void* d_ws, size_t ws_size,
                              hipStream_t stream)
{
    (void)in_sizes; (void)n_in; (void)out_size; (void)ws_size;

    const float* x      = (const float*)d_in[0];
    const float* kcache = (const float*)d_in[1];
    const float* vcache = (const float*)d_in[2];
    const int*   mask   = (const int*)  d_in[3];
    const float* Wq     = (const float*)d_in[4];
    const float* bq     = (const float*)d_in[5];
    const float* Wk     = (const float*)d_in[6];
    const float* bk     = (const float*)d_in[7];
    const float* Wv     = (const float*)d_in[8];
    const float* bv     = (const float*)d_in[9];
    const float* Wo     = (const float*)d_in[10];
    const float* bo     = (const float*)d_in[11];

    float* out  = (float*)d_out;
    float* kout = out  + (size_t)MROWS * DM;
    float* vout = kout + (size_t)BS * KV * DM;

    // Compact ws layout with lifetime aliasing (total 44.1 MB):
    //   [0, 8MB)      Obuf (bf16, kernels 2-3); xb aliases its first 2MB (kernels 0-1)
    //   [8, 40MB)     Wqb, Wkb, Wvb, Wob (bf16, kernels 0-4)
    //   [40, 42MB)    qb (bf16, kernels 1-2); awsb aliases it (kernels 3-4)
    //   [44, 44.13MB) Lbuf (f32, kernels 2-3)
    char* wsb = (char*)d_ws;
    __hip_bfloat16* Obuf = (__hip_bfloat16*)wsb;                      // 8 MB
    __hip_bfloat16* xb   = (__hip_bfloat16*)wsb;                      // aliases Obuf head
    __hip_bfloat16* Wqb  = (__hip_bfloat16*)(wsb + (8u<<20));
    __hip_bfloat16* Wkb  = Wqb + (size_t)DM * DM;
    __hip_bfloat16* Wvb  = Wkb + (size_t)DM * DM;
    __hip_bfloat16* Wob  = Wvb + (size_t)DM * DM;
    __hip_bfloat16* qb   = (__hip_bfloat16*)(wsb + (40u<<20));        // 2 MB
    __hip_bfloat16* awsb = qb;                                        // aliases qb
    float* Lbuf          = (float*)(wsb + (44u<<20));                 // 128 KB

    // 0) convert x + weights to bf16
    dim3 gp(1024, 5, 1);
    prep_bf16<<<gp, 256, 0, stream>>>(x, Wq, Wk, Wv, Wo, xb, Wqb, Wkb, Wvb, Wob);

    // 1) QKV projections; q written pre-scaled bf16; K/V spliced into caches
    dim3 gq(MROWS/64, DM/64, 3);
    gemm_bt<<<gq, 256, 0, stream>>>(xb, Wqb, Wkb, Wvb, bq, bk, bv,
                                    nullptr, kout, vout, qb, 0b110, 0b001);

    // 2) fused K/V copy + attention partials
    dim3 gf(NH, BS, KCA);
    fused_kv_attn<<<gf, 256, 0, stream>>>(qb, kcache, vcache, mask,
                                          kout, vout, Obuf, Lbuf);

    // 3) normalize + sum chunk partials -> bf16 (overwrites qb)
    attn_combine<<<512, 256, 0, stream>>>(Obuf, Lbuf, awsb);

    // 4) output projection (bf16 operands)
    dim3 go(MROWS/64, DM/64, 1);
    gemm_bt<<<go, 256, 0, stream>>>(awsb, Wob, Wob, Wob, bo, bo, bo,
                                    out, out, out, nullptr, 0, 0);
}